// Round 8
// baseline (110.659 us; speedup 1.0000x reference)
//
#include <hip/hip_runtime.h>
#include <hip/hip_bf16.h>
#include <math.h>

typedef __attribute__((ext_vector_type(8))) __bf16 bf16x8;
typedef __attribute__((ext_vector_type(4))) __bf16 bf16x4;
typedef __attribute__((ext_vector_type(2))) __bf16 bf16x2;
typedef __attribute__((ext_vector_type(4))) float f32x4;

#define NPTS 1024
#define CIN 512
#define NSAMP 64
#define LDFT 520   // bf16 per Ft row: 512 + 8 pad
#define LDFO 136   // bf16 per Fo row: 128 + 8 pad

// Exact-order f32 local-coords to match numpy ref rounding (no FMA contraction):
__device__ __forceinline__ void local_coords(const float* q, float cx, float cy, float cz,
                                             const float R[9], float& l0, float& l1, float& l2) {
    float d0 = __fsub_rn(q[0], cx);
    float d1 = __fsub_rn(q[1], cy);
    float d2 = __fsub_rn(q[2], cz);
    l0 = __fadd_rn(__fadd_rn(__fmul_rn(d0, R[0]), __fmul_rn(d1, R[3])), __fmul_rn(d2, R[6]));
    l1 = __fadd_rn(__fadd_rn(__fmul_rn(d0, R[1]), __fmul_rn(d1, R[4])), __fmul_rn(d2, R[7]));
    l2 = __fadd_rn(__fadd_rn(__fmul_rn(d0, R[2]), __fmul_rn(d1, R[5])), __fmul_rn(d2, R[8]));
}

// ================= K1: mega-setup =================
// roles: [0,256) fgemm (b=bid>>7, half=(bid>>6)&1, n0=(bid&63)<<4)
//        [256,512) prep (o = bid-256): W2s re-layout, wxs, s2, b2
//        [512,2560) select (p-index = bid-512)
__global__ __launch_bounds__(256) void setup_kernel(
    const float* __restrict__ xyz, const float* __restrict__ rot,
    const float* __restrict__ crop, const float* __restrict__ feats,
    const float* __restrict__ W1, const float* __restrict__ W2,
    const float* __restrict__ g1, const float* __restrict__ be1,
    const float* __restrict__ m1, const float* __restrict__ v1,
    const float* __restrict__ g2, const float* __restrict__ be2,
    const float* __restrict__ m2, const float* __restrict__ v2,
    __bf16* __restrict__ W2s, float* __restrict__ wxs,
    float* __restrict__ s2, float* __restrict__ b2,
    __bf16* __restrict__ Fsb,
    unsigned short* __restrict__ seln_g, int* __restrict__ cnt_g,
    f32x4* __restrict__ lcsel_g) {
    __shared__ __align__(16) char U[22016];  // union across roles
    const int t = threadIdx.x;

    if (blockIdx.x < 256) {
        // ---------- fgemm role ----------
        __bf16(*Ft)[LDFT] = (__bf16(*)[LDFT])(U);
        __bf16(*Fo)[LDFO] = (__bf16(*)[LDFO])(U + 16640);
        float* s1l = (float*)(U + 20992);
        float* b1l = (float*)(U + 21504);
        const int rb = blockIdx.x;
        const int b = rb >> 7, half = (rb >> 6) & 1, n0 = (rb & 63) << 4;
        const int l = t & 63, w = t >> 6;
        const int lo = l & 15, kg = l >> 4;

        if (t < 128) {
            const int o = half * 128 + t;
            const float s = g1[o] / sqrtf(v1[o] + 1e-5f);
            s1l[t] = s;
            b1l[t] = be1[o] - m1[o] * s;
        }
        const float* fb = feats + (size_t)b * (CIN * NPTS) + n0;
        {
            const int n = t & 15;
            const int cq = (t >> 4) * 2;
            for (int i = 0; i < 16; ++i) {
                int c = i * 32 + cq;
                float v0 = fb[(size_t)c * NPTS + n];
                float v1v = fb[(size_t)(c + 1) * NPTS + n];
                bf16x2 pk = {(__bf16)v0, (__bf16)v1v};
                *(bf16x2*)(&Ft[n][c]) = pk;
            }
        }
        __syncthreads();

        f32x4 acc[2];
#pragma unroll
        for (int mt = 0; mt < 2; ++mt) acc[mt] = f32x4{0.f, 0.f, 0.f, 0.f};

#pragma unroll
        for (int ks = 0; ks < 16; ++ks) {
            const int kk = ks * 32 + kg * 8;
            const bf16x8 bfr = *(const bf16x8*)(&Ft[lo][kk]);
#pragma unroll
            for (int mt = 0; mt < 2; ++mt) {
                const int o = half * 128 + w * 32 + mt * 16 + lo;
                const float* wrow = W1 + (size_t)o * 515 + 3 + kk;  // inline W1 cvt
                bf16x8 af;
#pragma unroll
                for (int j = 0; j < 8; ++j) af[j] = (__bf16)wrow[j];
                acc[mt] = __builtin_amdgcn_mfma_f32_16x16x32_bf16(af, bfr, acc[mt], 0, 0, 0);
            }
        }
        __syncthreads();
#pragma unroll
        for (int mt = 0; mt < 2; ++mt) {
            const int ol = w * 32 + mt * 16 + kg * 4;
            const f32x4 sv = *(const f32x4*)(&s1l[ol]);
            const f32x4 bv = *(const f32x4*)(&b1l[ol]);
            bf16x4 r;
#pragma unroll
            for (int j = 0; j < 4; ++j) r[j] = (__bf16)fmaf(acc[mt][j], sv[j], bv[j]);
            *(bf16x4*)(&Fo[lo][ol]) = r;
        }
        __syncthreads();
        {
            const int row = t >> 4, c = t & 15;
            const bf16x8 v = *(const bf16x8*)(&Fo[row][c * 8]);
            *(bf16x8*)(&Fsb[((size_t)(b * NPTS + n0 + row)) * 256 + half * 128 + c * 8]) = v;
        }
        return;
    }

    if (blockIdx.x < 512) {
        // ---------- prep role ----------
        const int o = blockIdx.x - 256;
        if (t == 0) {
            float sc1 = g1[o] / sqrtf(v1[o] + 1e-5f);
            float sc2 = g2[o] / sqrtf(v2[o] + 1e-5f);
            s2[o] = sc2;
            b2[o] = be2[o] - m2[o] * sc2;
            wxs[o * 4 + 0] = sc1 * W1[o * 515 + 0];
            wxs[o * 4 + 1] = sc1 * W1[o * 515 + 1];
            wxs[o * 4 + 2] = sc1 * W1[o * 515 + 2];
            wxs[o * 4 + 3] = 0.f;
        }
        // W2s[f]: f = ((((w*8+ks)*2+nt)*64)+l)*8 + j ; o2=w*32+nt*16+(l&15), k=ks*32+(l>>4)*8+j
        {
            const int f = o * 256 + t;
            const int j = f & 7;
            const int l = (f >> 3) & 63;
            const int nt = (f >> 9) & 1;
            const int ks = (f >> 10) & 7;
            const int w = (f >> 13) & 7;
            const int o2 = w * 32 + nt * 16 + (l & 15);
            const int k = ks * 32 + ((l >> 4) << 3) + j;
            W2s[f] = (__bf16)W2[o2 * 256 + k];
        }
        return;
    }

    // ---------- select role ----------
    f32x4* lcall = (f32x4*)(U);                         // [1024] 16KB
    unsigned long long* msk = (unsigned long long*)(U + 16384);  // [16]
    int* wpre = (int*)(U + 16512);                      // [17]
    int* selr = (int*)(U + 16584);                      // [64]
    const int bid = blockIdx.x - 512;
    const int b = bid >> 10;
    const int l = t & 63, w = t >> 6;

    const float cx = xyz[bid * 3 + 0], cy = xyz[bid * 3 + 1], cz = xyz[bid * 3 + 2];
    float R[9];
#pragma unroll
    for (int j = 0; j < 9; ++j) R[j] = rot[bid * 9 + j];
    const float h0 = 0.5f * crop[bid * 3 + 0];
    const float h1 = 0.5f * crop[bid * 3 + 1];
    const float h2 = 0.5f * crop[bid * 3 + 2];

#pragma unroll
    for (int i = 0; i < 4; ++i) {
        const int n = i * 256 + t;
        float l0, l1, l2;
        local_coords(xyz + (size_t)(b * NPTS + n) * 3, cx, cy, cz, R, l0, l1, l2);
        lcall[n] = f32x4{l0, l1, l2, 0.f};
        bool ins = (__builtin_fabsf(l0) <= h0) && (__builtin_fabsf(l1) <= h1) &&
                   (__builtin_fabsf(l2) <= h2);
        unsigned long long bal = __ballot(ins);
        if (l == 0) msk[i * 4 + w] = bal;
    }
    __syncthreads();
    if (t < 64) {
        const int c = (t < 16) ? __popcll(msk[t]) : 0;
        int sum = c;
#pragma unroll
        for (int d = 1; d < 16; d <<= 1) {
            int v = __shfl_up(sum, d);
            if (t >= d) sum += v;
        }
        if (t < 16) wpre[t] = sum - c;
        if (t == 15) wpre[16] = sum;
    }
    __syncthreads();
    const int cnt = wpre[16];
#pragma unroll
    for (int i = 0; i < 4; ++i) {
        const int n = i * 256 + t;
        const unsigned long long wd = msk[n >> 6];
        const int bit = n & 63;
        if ((wd >> bit) & 1ull) {
            int rank = wpre[n >> 6] + __popcll(wd & ((1ull << bit) - 1ull));
            if (rank < NSAMP) selr[rank] = n;
        }
    }
    __syncthreads();
    if (t < NSAMP) {
        const int n = selr[(t < cnt) ? t : 0];  // backfill; cnt>=1 (p inside own crop)
        seln_g[(size_t)bid * NSAMP + t] = (unsigned short)n;
        lcsel_g[(size_t)bid * NSAMP + t] = lcall[n];
    }
    if (t == 0) cnt_g[bid] = cnt;
}

// ================= K2: fused =================
// 512 blocks x 512 threads (8 waves); wave w owns o in [32w,32w+32); P=4 p per block.
// Build mapping: thread = (o-chunk of 4: t&63) x (row-group of 8: t>>6).
__global__ __launch_bounds__(512, 4) void fused_kernel(
    const __bf16* __restrict__ Fsb, const float* __restrict__ wxs,
    const unsigned short* __restrict__ seln_g, const int* __restrict__ cnt_g,
    const f32x4* __restrict__ lcsel_g,
    const __bf16* __restrict__ W2s, const float* __restrict__ s2g, const float* __restrict__ b2g,
    float* __restrict__ out) {
    __shared__ __align__(16) char A2raw[NSAMP * 512];   // bf16[64][256], XOR-swizzled
    __shared__ __align__(16) f32x4 lcL[4][NSAMP];
    __shared__ __align__(16) float outst[256][4];
    __shared__ unsigned short selL[4][NSAMP];
    __shared__ int cntL[4];

    // XCD-chunked bijective swizzle (512 = 8 * 64)
    const int raw = (int)blockIdx.x;
    const int pg = (raw & 7) * 64 + (raw >> 3);
    const int b = pg >> 8;
    const int p0 = (pg & 255) * 4;
    const int t = threadIdx.x;
    const int l = t & 63, w = t >> 6;
    const int lo = l & 15, kg = l >> 4;

    // LDS fill: selection metadata for all 4 p
    if (t < 256) {
        const int pi = t >> 6, s = t & 63;
        const size_t base = ((size_t)(b * NPTS + p0 + pi)) * NSAMP + s;
        selL[pi][s] = seln_g[base];
        lcL[pi][s] = lcsel_g[base];
    }
    if (t >= 256 && t < 260) cntL[t - 256] = cnt_g[b * NPTS + p0 + (t - 256)];

    // W2 fragments -> registers, resident whole kernel (64 VGPR)
    bf16x8 wf[8][2];
#pragma unroll
    for (int ks = 0; ks < 8; ++ks)
#pragma unroll
        for (int nt = 0; nt < 2; ++nt)
            wf[ks][nt] = *(const bf16x8*)(&W2s[(size_t)((((w * 8 + ks) * 2 + nt) * 64) + l) * 8]);

    // build mapping: o-chunk of 4, 8 rows per thread (row-group = wave)
    const int oc4 = (t & 63) * 4;
    const int g8 = t >> 6;  // 0..7
    f32x4 wv4[4];
#pragma unroll
    for (int j = 0; j < 4; ++j) wv4[j] = *(const f32x4*)(&wxs[(oc4 + j) * 4]);

    // BN2 params (p-invariant)
    float sc[2], bb[2];
#pragma unroll
    for (int nt = 0; nt < 2; ++nt) {
        const int o = w * 32 + nt * 16 + lo;
        sc[nt] = s2g[o];
        bb[nt] = b2g[o];
    }
    __syncthreads();

    bf16x4 stg[8];
    // ---- prologue: gather + transform + store A2 for p0 ----
    {
        const int rpad = (min(cntL[0], NSAMP) + 15) & ~15;
#pragma unroll
        for (int si = 0; si < 8; ++si) {
            const int s = g8 * 8 + si;
            if (s < rpad) {
                const int n = (int)selL[0][s];
                stg[si] = *(const bf16x4*)(&Fsb[((size_t)(b * NPTS + n)) * 256 + oc4]);
            }
        }
#pragma unroll
        for (int si = 0; si < 8; ++si) {
            const int s = g8 * 8 + si;
            if (s < rpad) {
                const f32x4 cd = lcL[0][s];
#pragma unroll
                for (int j = 0; j < 4; ++j) {
                    const float x = fmaf(cd.x, wv4[j].x,
                                         fmaf(cd.y, wv4[j].y,
                                              fmaf(cd.z, wv4[j].z, (float)stg[si][j])));
                    stg[si][j] = (__bf16)fmaxf(x, 0.f);
                }
                *(bf16x4*)(A2raw + s * 512 + ((oc4 * 2) ^ ((s & 7) << 4))) = stg[si];
            }
        }
    }
    __syncthreads();

    // ---- main loop over 4 p ----
    for (int pi = 0; pi < 4; ++pi) {
        const int mtmax = (min(cntL[pi], NSAMP) + 15) >> 4;
        int rpadn = 0;
        // issue-early: gather p_{pi+1} rows into regs
        if (pi < 3) {
            rpadn = (min(cntL[pi + 1], NSAMP) + 15) & ~15;
#pragma unroll
            for (int si = 0; si < 8; ++si) {
                const int s = g8 * 8 + si;
                if (s < rpadn) {
                    const int n = (int)selL[pi + 1][s];
                    stg[si] = *(const bf16x4*)(&Fsb[((size_t)(b * NPTS + n)) * 256 + oc4]);
                }
            }
        }

        // GEMM2(p) -- interleaves with transform(p+1) below (independent pipes)
        f32x4 acc[4][2];
#pragma unroll
        for (int mt = 0; mt < 4; ++mt)
#pragma unroll
            for (int nt = 0; nt < 2; ++nt)
                acc[mt][nt] = f32x4{0.f, 0.f, 0.f, 0.f};

#pragma unroll
        for (int mt = 0; mt < 4; ++mt) {
            if (mt < mtmax) {
                const int row = mt * 16 + lo;
#pragma unroll
                for (int ks = 0; ks < 8; ++ks) {
                    const bf16x8 a = *(const bf16x8*)(A2raw + row * 512 +
                                                      ((ks * 64 + kg * 16) ^ ((row & 7) << 4)));
                    acc[mt][0] = __builtin_amdgcn_mfma_f32_16x16x32_bf16(a, wf[ks][0],
                                                                         acc[mt][0], 0, 0, 0);
                    acc[mt][1] = __builtin_amdgcn_mfma_f32_16x16x32_bf16(a, wf[ks][1],
                                                                         acc[mt][1], 0, 0, 0);
                }
            }
        }

        // transform(p+1): pure-register VALU, co-issues with GEMM2 above
        if (pi < 3) {
#pragma unroll
            for (int si = 0; si < 8; ++si) {
                const int s = g8 * 8 + si;
                if (s < rpadn) {
                    const f32x4 cd = lcL[pi + 1][s];
#pragma unroll
                    for (int j = 0; j < 4; ++j) {
                        const float x = fmaf(cd.x, wv4[j].x,
                                             fmaf(cd.y, wv4[j].y,
                                                  fmaf(cd.z, wv4[j].z, (float)stg[si][j])));
                        stg[si][j] = (__bf16)fmaxf(x, 0.f);
                    }
                }
            }
        }

        // BN2 + relu + max over rows
#pragma unroll
        for (int nt = 0; nt < 2; ++nt) {
            float mx = 0.f;
#pragma unroll
            for (int mt = 0; mt < 4; ++mt) {
                if (mt < mtmax) {
#pragma unroll
                    for (int r = 0; r < 4; ++r)
                        mx = fmaxf(mx, fmaxf(fmaf(acc[mt][nt][r], sc[nt], bb[nt]), 0.f));
                }
            }
            mx = fmaxf(mx, __shfl_xor(mx, 16));
            mx = fmaxf(mx, __shfl_xor(mx, 32));
            if (kg == 0) outst[w * 32 + nt * 16 + lo][pi] = mx;
        }
        __syncthreads();  // BAR1: A2(p) fully consumed

        // short serial window: store transformed rows of p+1
        if (pi < 3) {
#pragma unroll
            for (int si = 0; si < 8; ++si) {
                const int s = g8 * 8 + si;
                if (s < rpadn)
                    *(bf16x4*)(A2raw + s * 512 + ((oc4 * 2) ^ ((s & 7) << 4))) = stg[si];
            }
        }
        __syncthreads();  // BAR2: A2(p+1) ready
    }

    // coalesced output: out[b][o][p0..p0+3]
    if (t < 256) {
        const int o = t;
        const f32x4 v = *(const f32x4*)(&outst[o][0]);
        *(f32x4*)(&out[((size_t)b * 256 + o) * NPTS + p0]) = v;
    }
}

extern "C" void kernel_launch(void* const* d_in, const int* in_sizes, int n_in,
                              void* d_out, int out_size, void* d_ws, size_t ws_size,
                              hipStream_t stream) {
    (void)in_sizes; (void)n_in; (void)out_size; (void)ws_size;
    const float* xyz   = (const float*)d_in[0];
    const float* feats = (const float*)d_in[1];
    const float* rot   = (const float*)d_in[2];
    const float* crop  = (const float*)d_in[3];
    const float* W1    = (const float*)d_in[4];
    const float* g1    = (const float*)d_in[5];
    const float* be1   = (const float*)d_in[6];
    const float* m1    = (const float*)d_in[7];
    const float* v1    = (const float*)d_in[8];
    const float* W2    = (const float*)d_in[9];
    const float* g2    = (const float*)d_in[10];
    const float* be2   = (const float*)d_in[11];
    const float* m2    = (const float*)d_in[12];
    const float* v2    = (const float*)d_in[13];

    char* ws = (char*)d_ws;
    __bf16* W2s = (__bf16*)(ws + 0);            // 131072
    float*  wxs = (float*)(ws + 131072);        // 4096
    float*  s2  = (float*)(ws + 135168);        // 1024
    float*  b2  = (float*)(ws + 136192);        // 1024
    __bf16* Fsb = (__bf16*)(ws + 137216);       // 1048576 -> 1185792
    unsigned short* seln = (unsigned short*)(ws + 1185792);  // 262144 -> 1447936
    int*    cntg = (int*)(ws + 1447936);        // 8192 -> 1456128
    f32x4*  lcse = (f32x4*)(ws + 1456128);      // 2097152 -> 3553280

    setup_kernel<<<2560, 256, 0, stream>>>(xyz, rot, crop, feats,
                                           W1, W2, g1, be1, m1, v1, g2, be2, m2, v2,
                                           W2s, wxs, s2, b2, Fsb, seln, cntg, lcse);
    fused_kernel<<<512, 512, 0, stream>>>(Fsb, wxs, seln, cntg, lcse, W2s, s2, b2,
                                          (float*)d_out);
}

// Round 9
// 44.162 us; speedup vs baseline: 2.5057x; 2.5057x over previous
//
#include <hip/hip_runtime.h>
#include <hip/hip_bf16.h>
#include <math.h>

typedef __attribute__((ext_vector_type(8))) __bf16 bf16x8;
typedef __attribute__((ext_vector_type(4))) __bf16 bf16x4;
typedef __attribute__((ext_vector_type(2))) __bf16 bf16x2;
typedef __attribute__((ext_vector_type(4))) float f32x4;

#define NPTS 1024
#define CIN 512
#define NSAMP 64
#define LDFT 520   // bf16 per Ft row: 512 + 8 pad
#define LDFO 136   // bf16 per Fo row: 128 + 8 pad

// Exact-order f32 local-coords to match numpy ref rounding (no FMA contraction):
__device__ __forceinline__ void local_coords(const float* q, float cx, float cy, float cz,
                                             const float R[9], float& l0, float& l1, float& l2) {
    float d0 = __fsub_rn(q[0], cx);
    float d1 = __fsub_rn(q[1], cy);
    float d2 = __fsub_rn(q[2], cz);
    l0 = __fadd_rn(__fadd_rn(__fmul_rn(d0, R[0]), __fmul_rn(d1, R[3])), __fmul_rn(d2, R[6]));
    l1 = __fadd_rn(__fadd_rn(__fmul_rn(d0, R[1]), __fmul_rn(d1, R[4])), __fmul_rn(d2, R[7]));
    l2 = __fadd_rn(__fadd_rn(__fmul_rn(d0, R[2]), __fmul_rn(d1, R[5])), __fmul_rn(d2, R[8]));
}

// -------- setup: blocks [0,256) = prep; blocks [256,2304) = select --------
__global__ __launch_bounds__(256) void setup_kernel(
    const float* __restrict__ xyz, const float* __restrict__ rot,
    const float* __restrict__ crop,
    const float* __restrict__ W1, const float* __restrict__ W2,
    const float* __restrict__ g1, const float* __restrict__ be1,
    const float* __restrict__ m1, const float* __restrict__ v1,
    const float* __restrict__ g2, const float* __restrict__ be2,
    const float* __restrict__ m2, const float* __restrict__ v2,
    __bf16* __restrict__ W1f, __bf16* __restrict__ W2s,
    float* __restrict__ wxs,
    float* __restrict__ s1, float* __restrict__ b1,
    float* __restrict__ s2, float* __restrict__ b2,
    unsigned short* __restrict__ seln_g, int* __restrict__ cnt_g,
    f32x4* __restrict__ lcsel_g) {
    __shared__ __align__(16) f32x4 lcall[NPTS];  // 16KB: coords of all points
    __shared__ unsigned long long msk[16];
    __shared__ int wpre[17];
    __shared__ int selr[NSAMP];

    const int t = threadIdx.x;
    if (blockIdx.x < 256) {
        // ---- prep role ----
        const int o = blockIdx.x;
        if (t == 0) {
            float sc1 = g1[o] / sqrtf(v1[o] + 1e-5f);
            s1[o] = sc1;
            b1[o] = be1[o] - m1[o] * sc1;
            float sc2 = g2[o] / sqrtf(v2[o] + 1e-5f);
            s2[o] = sc2;
            b2[o] = be2[o] - m2[o] * sc2;
            wxs[o * 4 + 0] = sc1 * W1[o * 515 + 0];
            wxs[o * 4 + 1] = sc1 * W1[o * 515 + 1];
            wxs[o * 4 + 2] = sc1 * W1[o * 515 + 2];
            wxs[o * 4 + 3] = 0.f;
        }
        for (int k = t; k < CIN; k += blockDim.x)
            W1f[o * CIN + k] = (__bf16)W1[o * 515 + 3 + k];
        // W2s[f]: f = ((((w*8+ks)*2+nt)*64)+l)*8 + j ; o2=w*32+nt*16+(l&15), k=ks*32+(l>>4)*8+j
        {
            const int f = o * 256 + t;
            const int j = f & 7;
            const int l = (f >> 3) & 63;
            const int nt = (f >> 9) & 1;
            const int ks = (f >> 10) & 7;
            const int w = (f >> 13) & 7;
            const int o2 = w * 32 + nt * 16 + (l & 15);
            const int k = ks * 32 + ((l >> 4) << 3) + j;
            W2s[f] = (__bf16)W2[o2 * 256 + k];
        }
        return;
    }
    // ---- select role ----
    const int bid = blockIdx.x - 256;
    const int b = bid >> 10;
    const int l = t & 63, w = t >> 6;

    const float cx = xyz[bid * 3 + 0], cy = xyz[bid * 3 + 1], cz = xyz[bid * 3 + 2];
    float R[9];
#pragma unroll
    for (int j = 0; j < 9; ++j) R[j] = rot[bid * 9 + j];
    const float h0 = 0.5f * crop[bid * 3 + 0];
    const float h1 = 0.5f * crop[bid * 3 + 1];
    const float h2 = 0.5f * crop[bid * 3 + 2];

#pragma unroll
    for (int i = 0; i < 4; ++i) {
        const int n = i * 256 + t;
        float l0, l1, l2;
        local_coords(xyz + (size_t)(b * NPTS + n) * 3, cx, cy, cz, R, l0, l1, l2);
        lcall[n] = f32x4{l0, l1, l2, 0.f};
        bool ins = (__builtin_fabsf(l0) <= h0) && (__builtin_fabsf(l1) <= h1) &&
                   (__builtin_fabsf(l2) <= h2);
        unsigned long long bal = __ballot(ins);
        if (l == 0) msk[i * 4 + w] = bal;
    }
    __syncthreads();
    if (t < 64) {
        const int c = (t < 16) ? __popcll(msk[t]) : 0;
        int sum = c;
#pragma unroll
        for (int d = 1; d < 16; d <<= 1) {
            int v = __shfl_up(sum, d);
            if (t >= d) sum += v;
        }
        if (t < 16) wpre[t] = sum - c;
        if (t == 15) wpre[16] = sum;
    }
    __syncthreads();
    const int cnt = wpre[16];
#pragma unroll
    for (int i = 0; i < 4; ++i) {
        const int n = i * 256 + t;
        const unsigned long long wd = msk[n >> 6];
        const int bit = n & 63;
        if ((wd >> bit) & 1ull) {
            int rank = wpre[n >> 6] + __popcll(wd & ((1ull << bit) - 1ull));
            if (rank < NSAMP) selr[rank] = n;
        }
    }
    __syncthreads();
    if (t < NSAMP) {
        const int n = selr[(t < cnt) ? t : 0];  // backfill; cnt>=1 (p inside own crop)
        seln_g[(size_t)bid * NSAMP + t] = (unsigned short)n;
        lcsel_g[(size_t)bid * NSAMP + t] = lcall[n];
    }
    if (t == 0) cnt_g[bid] = cnt;
}

// ------- F-GEMM: Fsb[b][n][o] = bf16(s1[o]*(sum_c feats[b][c][n]*W1f[o][c]) + b1[o]) -------
__global__ __launch_bounds__(256) void fgemm_kernel(const float* __restrict__ feats,
                                                    const __bf16* __restrict__ W1f,
                                                    const float* __restrict__ s1,
                                                    const float* __restrict__ b1,
                                                    __bf16* __restrict__ Fsb) {
    __shared__ __align__(16) __bf16 Ft[16][LDFT];
    __shared__ __align__(16) __bf16 Fo[16][LDFO];
    const int t = threadIdx.x;
    const int b = blockIdx.x >> 7;
    const int half = (blockIdx.x >> 6) & 1;
    const int n0 = (blockIdx.x & 63) << 4;
    const int l = t & 63, w = t >> 6;
    const int lo = l & 15, kg = l >> 4;

    const float* fb = feats + (size_t)b * (CIN * NPTS) + n0;
    {
        const int n = t & 15;
        const int cq = (t >> 4) * 2;
        for (int i = 0; i < 16; ++i) {
            int c = i * 32 + cq;
            float v0 = fb[(size_t)c * NPTS + n];
            float v1v = fb[(size_t)(c + 1) * NPTS + n];
            bf16x2 pk = {(__bf16)v0, (__bf16)v1v};
            *(bf16x2*)(&Ft[n][c]) = pk;
        }
    }
    __syncthreads();

    f32x4 acc[2];
#pragma unroll
    for (int mt = 0; mt < 2; ++mt) acc[mt] = f32x4{0.f, 0.f, 0.f, 0.f};

#pragma unroll
    for (int ks = 0; ks < 16; ++ks) {
        const int kk = ks * 32 + kg * 8;
        const bf16x8 bfr = *(const bf16x8*)(&Ft[lo][kk]);
#pragma unroll
        for (int mt = 0; mt < 2; ++mt) {
            const int o = half * 128 + w * 32 + mt * 16 + lo;
            const bf16x8 af = *(const bf16x8*)(&W1f[(size_t)o * CIN + kk]);
            acc[mt] = __builtin_amdgcn_mfma_f32_16x16x32_bf16(af, bfr, acc[mt], 0, 0, 0);
        }
    }
    __syncthreads();
#pragma unroll
    for (int mt = 0; mt < 2; ++mt) {
        const int ol = w * 32 + mt * 16 + kg * 4;
        const f32x4 sv = *(const f32x4*)(&s1[half * 128 + ol]);
        const f32x4 bv = *(const f32x4*)(&b1[half * 128 + ol]);
        bf16x4 r;
#pragma unroll
        for (int j = 0; j < 4; ++j) r[j] = (__bf16)fmaf(acc[mt][j], sv[j], bv[j]);
        *(bf16x4*)(&Fo[lo][ol]) = r;
    }
    __syncthreads();
    {
        const int row = t >> 4, c = t & 15;
        const bf16x8 v = *(const bf16x8*)(&Fo[row][c * 8]);
        *(bf16x8*)(&Fsb[((size_t)(b * NPTS + n0 + row)) * 256 + half * 128 + c * 8]) = v;
    }
}

// -------- fused: weight-stationary, cnt-bounded GEMM2, P=8 p per block --------
// 256 blocks x 512 threads (8 waves); wave w owns o in [32w,32w+32).
// Build/gather mapping: thread = (o-chunk of 4: t&63) x (row-group of 8: t>>6).
__global__ __launch_bounds__(512, 2) void fused_kernel(
    const __bf16* __restrict__ Fsb, const float* __restrict__ wxs,
    const unsigned short* __restrict__ seln_g, const int* __restrict__ cnt_g,
    const f32x4* __restrict__ lcsel_g,
    const __bf16* __restrict__ W2s, const float* __restrict__ s2g, const float* __restrict__ b2g,
    float* __restrict__ out) {
    __shared__ __align__(16) char A2raw[NSAMP * 512];   // bf16[64][256], XOR-swizzled
    __shared__ __align__(16) f32x4 lcL[8][NSAMP];
    __shared__ __align__(16) float outst[256][8];
    __shared__ unsigned short selL[8][NSAMP];
    __shared__ int cntL[8];

    // XCD-chunked bijective swizzle (256 = 8 * 32)
    const int raw = (int)blockIdx.x;
    const int pg = (raw & 7) * 32 + (raw >> 3);
    const int b = pg >> 7;
    const int p0 = (pg & 127) * 8;
    const int t = threadIdx.x;
    const int l = t & 63, w = t >> 6;
    const int lo = l & 15, kg = l >> 4;

    // LDS fill: selection metadata for all 8 p (all 512 threads)
    {
        const int pi = t >> 6, s = t & 63;
        const size_t base = ((size_t)(b * NPTS + p0 + pi)) * NSAMP + s;
        selL[pi][s] = seln_g[base];
        lcL[pi][s] = lcsel_g[base];
    }
    if (t < 8) cntL[t] = cnt_g[b * NPTS + p0 + t];

    // W2 fragments -> registers, resident whole kernel (64 VGPR)
    bf16x8 wf[8][2];
#pragma unroll
    for (int ks = 0; ks < 8; ++ks)
#pragma unroll
        for (int nt = 0; nt < 2; ++nt)
            wf[ks][nt] = *(const bf16x8*)(&W2s[(size_t)((((w * 8 + ks) * 2 + nt) * 64) + l) * 8]);

    // build mapping: o-chunk of 4, 8 rows per thread (row-group = wave)
    const int oc4 = (t & 63) * 4;
    const int g8 = t >> 6;  // 0..7
    f32x4 wv4[4];
#pragma unroll
    for (int j = 0; j < 4; ++j) wv4[j] = *(const f32x4*)(&wxs[(oc4 + j) * 4]);

    // BN2 params (p-invariant)
    float sc[2], bb[2];
#pragma unroll
    for (int nt = 0; nt < 2; ++nt) {
        const int o = w * 32 + nt * 16 + lo;
        sc[nt] = s2g[o];
        bb[nt] = b2g[o];
    }
    __syncthreads();

    bf16x4 stg[8];
    // ---- prologue: gather + transform + store A2 for p0 ----
    {
        const int rpad = (min(cntL[0], NSAMP) + 15) & ~15;
#pragma unroll
        for (int si = 0; si < 8; ++si) {
            const int s = g8 * 8 + si;
            if (s < rpad) {
                const int n = (int)selL[0][s];
                stg[si] = *(const bf16x4*)(&Fsb[((size_t)(b * NPTS + n)) * 256 + oc4]);
            }
        }
#pragma unroll
        for (int si = 0; si < 8; ++si) {
            const int s = g8 * 8 + si;
            if (s < rpad) {
                const f32x4 cd = lcL[0][s];
#pragma unroll
                for (int j = 0; j < 4; ++j) {
                    const float x = fmaf(cd.x, wv4[j].x,
                                         fmaf(cd.y, wv4[j].y,
                                              fmaf(cd.z, wv4[j].z, (float)stg[si][j])));
                    stg[si][j] = (__bf16)fmaxf(x, 0.f);
                }
                *(bf16x4*)(A2raw + s * 512 + ((oc4 * 2) ^ ((s & 7) << 4))) = stg[si];
            }
        }
    }
    __syncthreads();

    // ---- main loop over 8 p ----
    for (int pi = 0; pi < 8; ++pi) {
        const int mtmax = (min(cntL[pi], NSAMP) + 15) >> 4;
        int rpadn = 0;
        // issue-early: gather p_{pi+1} rows into regs
        if (pi < 7) {
            rpadn = (min(cntL[pi + 1], NSAMP) + 15) & ~15;
#pragma unroll
            for (int si = 0; si < 8; ++si) {
                const int s = g8 * 8 + si;
                if (s < rpadn) {
                    const int n = (int)selL[pi + 1][s];
                    stg[si] = *(const bf16x4*)(&Fsb[((size_t)(b * NPTS + n)) * 256 + oc4]);
                }
            }
        }

        // GEMM2(p) on current A2 (W2 in registers)
        f32x4 acc[4][2];
#pragma unroll
        for (int mt = 0; mt < 4; ++mt)
#pragma unroll
            for (int nt = 0; nt < 2; ++nt)
                acc[mt][nt] = f32x4{0.f, 0.f, 0.f, 0.f};

#pragma unroll
        for (int mt = 0; mt < 4; ++mt) {
            if (mt < mtmax) {
                const int row = mt * 16 + lo;
#pragma unroll
                for (int ks = 0; ks < 8; ++ks) {
                    const bf16x8 a = *(const bf16x8*)(A2raw + row * 512 +
                                                      ((ks * 64 + kg * 16) ^ ((row & 7) << 4)));
                    acc[mt][0] = __builtin_amdgcn_mfma_f32_16x16x32_bf16(a, wf[ks][0],
                                                                         acc[mt][0], 0, 0, 0);
                    acc[mt][1] = __builtin_amdgcn_mfma_f32_16x16x32_bf16(a, wf[ks][1],
                                                                         acc[mt][1], 0, 0, 0);
                }
            }
        }

        // transform(p+1): pure-register VALU, co-issues with GEMM2 above
        if (pi < 7) {
#pragma unroll
            for (int si = 0; si < 8; ++si) {
                const int s = g8 * 8 + si;
                if (s < rpadn) {
                    const f32x4 cd = lcL[pi + 1][s];
#pragma unroll
                    for (int j = 0; j < 4; ++j) {
                        const float x = fmaf(cd.x, wv4[j].x,
                                             fmaf(cd.y, wv4[j].y,
                                                  fmaf(cd.z, wv4[j].z, (float)stg[si][j])));
                        stg[si][j] = (__bf16)fmaxf(x, 0.f);
                    }
                }
            }
        }

        // BN2 + relu + max over rows
#pragma unroll
        for (int nt = 0; nt < 2; ++nt) {
            float mx = 0.f;
#pragma unroll
            for (int mt = 0; mt < 4; ++mt) {
                if (mt < mtmax) {
#pragma unroll
                    for (int r = 0; r < 4; ++r)
                        mx = fmaxf(mx, fmaxf(fmaf(acc[mt][nt][r], sc[nt], bb[nt]), 0.f));
                }
            }
            mx = fmaxf(mx, __shfl_xor(mx, 16));
            mx = fmaxf(mx, __shfl_xor(mx, 32));
            if (kg == 0) outst[w * 32 + nt * 16 + lo][pi] = mx;
        }
        __syncthreads();  // BAR1: A2(p) fully consumed

        // short serial window: store transformed rows of p+1
        if (pi < 7) {
#pragma unroll
            for (int si = 0; si < 8; ++si) {
                const int s = g8 * 8 + si;
                if (s < rpadn)
                    *(bf16x4*)(A2raw + s * 512 + ((oc4 * 2) ^ ((s & 7) << 4))) = stg[si];
            }
        }
        __syncthreads();  // BAR2: A2(p+1) ready
    }

    // ---- coalesced output: out[b][o][p0..p0+7] ----
    {
        const int o = t >> 1, hf = t & 1;
        const f32x4 v = *(const f32x4*)(&outst[o][hf * 4]);
        *(f32x4*)(&out[((size_t)b * 256 + o) * NPTS + p0 + hf * 4]) = v;
    }
}

extern "C" void kernel_launch(void* const* d_in, const int* in_sizes, int n_in,
                              void* d_out, int out_size, void* d_ws, size_t ws_size,
                              hipStream_t stream) {
    (void)in_sizes; (void)n_in; (void)out_size; (void)ws_size;
    const float* xyz   = (const float*)d_in[0];
    const float* feats = (const float*)d_in[1];
    const float* rot   = (const float*)d_in[2];
    const float* crop  = (const float*)d_in[3];
    const float* W1    = (const float*)d_in[4];
    const float* g1    = (const float*)d_in[5];
    const float* be1   = (const float*)d_in[6];
    const float* m1    = (const float*)d_in[7];
    const float* v1    = (const float*)d_in[8];
    const float* W2    = (const float*)d_in[9];
    const float* g2    = (const float*)d_in[10];
    const float* be2   = (const float*)d_in[11];
    const float* m2    = (const float*)d_in[12];
    const float* v2    = (const float*)d_in[13];

    char* ws = (char*)d_ws;
    __bf16* W1f = (__bf16*)(ws + 0);            // 262144
    __bf16* W2s = (__bf16*)(ws + 262144);       // 131072
    float*  wxs = (float*)(ws + 393216);        // 4096
    float*  s1  = (float*)(ws + 397312);
    float*  b1  = (float*)(ws + 398336);
    float*  s2  = (float*)(ws + 399360);
    float*  b2  = (float*)(ws + 400384);
    __bf16* Fsb = (__bf16*)(ws + 401408);       // 1048576 -> ends 1449984
    unsigned short* seln = (unsigned short*)(ws + 1449984);  // 262144 -> ends 1712128
    int*    cntg = (int*)(ws + 1712128);        // 8192 -> ends 1720320
    f32x4*  lcse = (f32x4*)(ws + 1720320);      // 2097152 -> ends 3817472

    setup_kernel<<<2304, 256, 0, stream>>>(xyz, rot, crop,
                                           W1, W2, g1, be1, m1, v1, g2, be2, m2, v2,
                                           W1f, W2s, wxs, s1, b1, s2, b2, seln, cntg, lcse);
    fgemm_kernel<<<256, 256, 0, stream>>>(feats, W1f, s1, b1, Fsb);
    fused_kernel<<<256, 512, 0, stream>>>(Fsb, wxs, seln, cntg, lcse, W2s, s2, b2,
                                          (float*)d_out);
}